// Round 18
// baseline (862.677 us; speedup 1.0000x reference)
//
#include <hip/hip_runtime.h>

// ---------- types / helpers ----------
typedef _Float16 f16x8 __attribute__((ext_vector_type(8)));
typedef _Float16 f16x4 __attribute__((ext_vector_type(4)));
typedef __attribute__((ext_vector_type(4))) float f32x4;
typedef __attribute__((ext_vector_type(4))) unsigned int u32x4;

#define DI __device__ __forceinline__

DI void gload16(const void* g, void* l) {
  __builtin_amdgcn_global_load_lds(
      (const __attribute__((address_space(1))) unsigned int*)g,
      (__attribute__((address_space(3))) unsigned int*)l, 16, 0, 0);
}

DI float sigm(float x) { return 1.f / (1.f + __expf(-x)); }
DI float tanh_(float x) { return 2.f / (1.f + __expf(-2.f * x)) - 1.f; }

// ---------- f32 -> f16 conversion (x4) ----------
__global__ __launch_bounds__(256) void cvt4h(const float* __restrict__ in,
                                             _Float16* __restrict__ out, int n4) {
  int i = blockIdx.x * 256 + threadIdx.x;
  if (i >= n4) return;
  float4 v = ((const float4*)in)[i];
  f16x4 o;
  o[0] = (_Float16)v.x; o[1] = (_Float16)v.y; o[2] = (_Float16)v.z; o[3] = (_Float16)v.w;
  ((f16x4*)out)[i] = o;
}

// ---------- 256x256 f16 GEMM (R13 exact — best measured: 260us, 0 conflicts) ----------
__global__ __launch_bounds__(512, 2)
void gemm256(const _Float16* __restrict__ A, const _Float16* __restrict__ B,
             _Float16* __restrict__ C, int M, int N, int K) {
  extern __shared__ _Float16 sm[];         // [2][16384] A | [2][16384] B
  _Float16* smA = sm;
  _Float16* smB = sm + 32768;

  const int t512 = threadIdx.x;
  const int lane = t512 & 63, wid = t512 >> 6;
  const int wm = (wid >> 2) * 128, wn = (wid & 3) * 64;
  const int lr = lane & 15, lg = lane >> 4;
  const int sg0 = lg ^ (lr & 7), sg1 = (4 + lg) ^ (lr & 7);  // swizzled k-granules

  const int nwgx = gridDim.x;
  int id = blockIdx.y * nwgx + blockIdx.x;
  int nwg = nwgx * gridDim.y;
  if ((nwg & 7) == 0) id = (id & 7) * (nwg >> 3) + (id >> 3);
  const int n0 = (id % nwgx) * 256;
  const int m0 = (id / nwgx) * 256;

  f32x4 acc[8][4] = {};

#define STAGE(kt, buf)                                                         \
  {                                                                            \
    const int kbase = (kt) * 64;                                               \
    _Pragma("unroll") for (int i = 0; i < 4; ++i) {                            \
      int G = t512 + i * 512;                                                  \
      int r = G >> 3, gs = (G & 7) ^ (r & 7);                                  \
      gload16(A + (size_t)(m0 + r) * K + kbase + gs * 8,                       \
              smA + (buf) * 16384 + G * 8);                                    \
    }                                                                          \
    _Pragma("unroll") for (int i = 0; i < 4; ++i) {                            \
      int G = t512 + i * 512;                                                  \
      int r = G >> 3, gs = (G & 7) ^ (r & 7);                                  \
      gload16(B + (size_t)(n0 + r) * K + kbase + gs * 8,                       \
              smB + (buf) * 16384 + G * 8);                                    \
    }                                                                          \
  }

#define PHASE(m0f, n0f)                                                        \
  {                                                                            \
    f16x8 av[4][2], bv[2][2];                                                  \
    _Pragma("unroll") for (int im = 0; im < 4; ++im) {                         \
      int row = wm + (m0f + im) * 16 + lr;                                     \
      av[im][0] = *(const f16x8*)(Ab + row * 128 + sg0 * 16);                  \
      av[im][1] = *(const f16x8*)(Ab + row * 128 + sg1 * 16);                  \
    }                                                                          \
    _Pragma("unroll") for (int jn = 0; jn < 2; ++jn) {                         \
      int row = wn + (n0f + jn) * 16 + lr;                                     \
      bv[jn][0] = *(const f16x8*)(Bb + row * 128 + sg0 * 16);                  \
      bv[jn][1] = *(const f16x8*)(Bb + row * 128 + sg1 * 16);                  \
    }                                                                          \
    _Pragma("unroll") for (int im = 0; im < 4; ++im)                           \
        _Pragma("unroll") for (int jn = 0; jn < 2; ++jn) {                     \
      acc[m0f + im][n0f + jn] = __builtin_amdgcn_mfma_f32_16x16x32_f16(        \
          av[im][0], bv[jn][0], acc[m0f + im][n0f + jn], 0, 0, 0);             \
      acc[m0f + im][n0f + jn] = __builtin_amdgcn_mfma_f32_16x16x32_f16(        \
          av[im][1], bv[jn][1], acc[m0f + im][n0f + jn], 0, 0, 0);             \
    }                                                                          \
  }

  STAGE(0, 0);
  const int NT = K >> 6;
  for (int t = 0; t < NT; ++t) {
    const int c = t & 1;
    if (t + 1 < NT) {
      STAGE(t + 1, c ^ 1);
      asm volatile("s_waitcnt vmcnt(8)" ::: "memory");  // tile t done; t+1 in flight
    } else {
      asm volatile("s_waitcnt vmcnt(0)" ::: "memory");
    }
    __builtin_amdgcn_s_barrier();
    __builtin_amdgcn_sched_barrier(0);   // fence: no ds_read above barrier
    const char* Ab = (const char*)(smA + c * 16384);
    const char* Bb = (const char*)(smB + c * 16384);
    PHASE(0, 0)
    PHASE(0, 2)
    PHASE(4, 0)
    PHASE(4, 2)
    __builtin_amdgcn_s_barrier();
    __builtin_amdgcn_sched_barrier(0);   // fence: no gload-LDS-write above barrier
  }
#undef STAGE
#undef PHASE

#pragma unroll
  for (int m = 0; m < 8; ++m)
#pragma unroll
    for (int n = 0; n < 4; ++n)
#pragma unroll
      for (int q = 0; q < 4; ++q) {
        int row = m0 + wm + m * 16 + lg * 4 + q;
        int col = n0 + wn + n * 16 + lr;
        C[(size_t)row * N + col] = (_Float16)acc[m][n][q];
      }
}

// ---------- f16 GEMM: C[M,N] = A[M,K] * B[N,K]^T  (m97 structure; xg GEMM) ----------
template <int OUTMODE>
__global__ __launch_bounds__(256, 2)
void gemm_bt(const _Float16* __restrict__ A, const _Float16* __restrict__ B,
             void* __restrict__ Cout, const float* __restrict__ bias1,
             const float* __restrict__ bias2, int M, int N, int K) {
  __shared__ alignas(16) _Float16 Asm[128 * 32];
  __shared__ alignas(16) _Float16 Bsm[128 * 32];
  const int t = threadIdx.x;
  const int lane = t & 63, wid = t >> 6;
  const int m0 = blockIdx.y * 128, n0 = blockIdx.x * 128;
  const int wm = (wid >> 1) * 64, wn = (wid & 1) * 64;
  const int lr = lane & 15, lk = (lane >> 4) * 8, lg = lane >> 4;

  f32x4 acc[4][4] = {};

  const int e0 = t, e1 = t + 256;
  const int ra0 = e0 >> 2, ka0 = (e0 & 3) << 3;
  const int ra1 = e1 >> 2, ka1 = (e1 & 3) << 3;

  for (int kt = 0; kt < K; kt += 32) {
    gload16(A + (size_t)(m0 + ra0) * K + kt + ka0, &Asm[e0 * 8]);
    gload16(A + (size_t)(m0 + ra1) * K + kt + ka1, &Asm[e1 * 8]);
    gload16(B + (size_t)(n0 + ra0) * K + kt + ka0, &Bsm[e0 * 8]);
    gload16(B + (size_t)(n0 + ra1) * K + kt + ka1, &Bsm[e1 * 8]);
    __syncthreads();
    f16x8 af[4], bfr[4];
#pragma unroll
    for (int f = 0; f < 4; ++f) {
      af[f] = *(const f16x8*)&Asm[(wm + f * 16 + lr) * 32 + lk];
      bfr[f] = *(const f16x8*)&Bsm[(wn + f * 16 + lr) * 32 + lk];
    }
#pragma unroll
    for (int i = 0; i < 4; ++i)
#pragma unroll
      for (int j = 0; j < 4; ++j)
        acc[i][j] = __builtin_amdgcn_mfma_f32_16x16x32_f16(af[i], bfr[j], acc[i][j], 0, 0, 0);
    __syncthreads();
  }

#pragma unroll
  for (int i = 0; i < 4; ++i) {
#pragma unroll
    for (int j = 0; j < 4; ++j) {
#pragma unroll
      for (int q = 0; q < 4; ++q) {
        int row = m0 + wm + i * 16 + lg * 4 + q;
        int col = n0 + wn + j * 16 + lr;
        if constexpr (OUTMODE == 0) {
          ((_Float16*)Cout)[(size_t)row * N + col] = (_Float16)acc[i][j][q];
        } else {
          ((float*)Cout)[(size_t)row * N + col] = acc[i][j][q] + bias1[col] + bias2[col];
        }
      }
    }
  }
}

// ---------- mix1 ----------
__global__ __launch_bounds__(256) void mix1(const _Float16* __restrict__ node1,
                                            const float* __restrict__ dist,
                                            _Float16* __restrict__ n1t) {
  __shared__ float ds[288];
  const int nt = blockIdx.x, tid = threadIdx.x;
  for (int i = tid; i < 288; i += 256)
    ds[i] = dist[(size_t)nt * 576 + 288 + i] + dist[(size_t)nt * 576 + i];
  __syncthreads();
  const int c = blockIdx.y * 256 + tid;  // 0..2047
  float s[12];
#pragma unroll
  for (int w = 0; w < 12; ++w) s[w] = 0.f;
#pragma unroll
  for (int k = 0; k < 2; ++k)
#pragma unroll
    for (int v = 0; v < 12; ++v) {
      float x = (float)node1[(size_t)(nt * 12 + v) * 4096 + k * 2048 + c];
      const float* d = &ds[k * 144 + v * 12];
#pragma unroll
      for (int w = 0; w < 12; ++w) s[w] = fmaf(x, d[w], s[w]);
    }
#pragma unroll
  for (int w = 0; w < 12; ++w)
    n1t[(size_t)(nt * 12 + w) * 2048 + c] = (_Float16)fmaxf(s[w], 0.f);
}

// ---------- mix2 + pooling ----------
__global__ __launch_bounds__(256) void mix2(const _Float16* __restrict__ node2,
                                            const float* __restrict__ dist,
                                            _Float16* __restrict__ pooled) {
  __shared__ float db[288], dc[288];
  const int nt = blockIdx.x, tid = threadIdx.x;
  for (int i = tid; i < 288; i += 256) {
    db[i] = dist[(size_t)nt * 576 + 288 + i];
    dc[i] = dist[(size_t)nt * 576 + i];
  }
  __syncthreads();
  const int c = blockIdx.y * 256 + tid;  // 0..1023
  float sb[12], sc[12];
#pragma unroll
  for (int w = 0; w < 12; ++w) { sb[w] = 0.f; sc[w] = 0.f; }
#pragma unroll
  for (int k = 0; k < 2; ++k)
#pragma unroll
    for (int v = 0; v < 12; ++v) {
      float x = (float)node2[(size_t)(nt * 12 + v) * 2048 + k * 1024 + c];
      const float* pb = &db[k * 144 + v * 12];
      const float* pc = &dc[k * 144 + v * 12];
#pragma unroll
      for (int w = 0; w < 12; ++w) { sb[w] = fmaf(x, pb[w], sb[w]); sc[w] = fmaf(x, pc[w], sc[w]); }
    }
  float left = 0.f, right = 0.f, allf = 0.f;
#pragma unroll
  for (int w = 0; w < 6; ++w) left += fmaxf(sb[w], 0.f);
#pragma unroll
  for (int w = 6; w < 12; ++w) right += fmaxf(sb[w], 0.f);
#pragma unroll
  for (int w = 0; w < 12; ++w) allf += fmaxf(sc[w], 0.f);
  pooled[(size_t)nt * 3072 + c] = (_Float16)(left * (1.f / 6.f));
  pooled[(size_t)nt * 3072 + 1024 + c] = (_Float16)(right * (1.f / 6.f));
  pooled[(size_t)nt * 3072 + 2048 + c] = (_Float16)(allf * (1.f / 12.f));
}

// ---------- persistent LSTM v5: 128 blocks x 16 cols (halve h-broadcast) ----------
// h-broadcast traffic = blocks x 80KB/step: 128 blocks -> 10MB/step (was 20).
// Block b owns cols cb..cb+15; wave w computes gate w (16 W rows). Gate 0's
// rows in LDS (64KB swizzled); gates 1-3 via cached global (per-XCD footprint
// 16 blocks x 192KB = 3MB < 4MB L2 - proven-safe R12 regime). Same uncached
// h protocol + store-only flag barrier.
__global__ __launch_bounds__(256, 1) void lstm_persist5(
    const _Float16* __restrict__ whh,   // [8192,2048] f16
    const float* __restrict__ xg,       // [640,8192]
    _Float16* __restrict__ hbuf,        // 2 buffers, stride 65536 elems
    float* __restrict__ vf,             // [32*20,2048] f32
    int* __restrict__ go,               // 8 lines x 64B (memset 0)
    int* __restrict__ flags) {          // lines x 64B (memset 0)
  extern __shared__ char lds[];
  char* hls = lds;                      // [20][256 granules x16B] swizzled (80KB)
  char* wls = lds + 81920;              // [16][256 granules x16B] swizzled (64KB)
  float* Y = (float*)(lds + 147456);    // [20][64]
  const int tid = threadIdx.x, bid = blockIdx.x, cb = bid * 16;
  const int lane = tid & 63, w = tid >> 6;         // wave = gate
  const int lr = lane & 15, lg = lane >> 4;
  const _Float16* wp = whh + (size_t)(w * 2048 + cb + lr) * 2048;
  const int arow1 = (lr < 4) ? (16 + lr) : (16 + (lr & 3));  // clamped m-tile1 row
  float c0 = 0.f, c1 = 0.f;                        // c-state: idx=tid, idx=tid+256

  // prologue: stage gate-0 W rows (cols cb..cb+15) into LDS, swizzled
  for (int i = tid; i < 4096; i += 256) {          // 16 rows x 256 granules
    int r = i >> 8, gg = i & 255;
    u32x4 v = *(const u32x4*)(whh + (size_t)(cb + r) * 2048 + gg * 8);
    *(u32x4*)(wls + ((r << 8) + (gg ^ (r & 7))) * 16) = v;
  }

  for (int s = 0; s < 32; ++s) {
    if (s > 0) {
      // stage h(s-1) -> LDS (swizzled), uncached coalesced 16B loads
      const _Float16* hsrc = hbuf + ((s - 1) & 1) * 65536;
      u32x4 tmp[20];
#pragma unroll
      for (int j = 0; j < 20; ++j) {
        asm volatile("global_load_dwordx4 %0, %1, off sc0 sc1"
                     : "=v"(tmp[j]) : "v"(hsrc + j * 2048 + tid * 8));
      }
      asm volatile("s_waitcnt vmcnt(0)" ::: "memory");
      __builtin_amdgcn_sched_barrier(0);
#pragma unroll
      for (int j = 0; j < 20; ++j)
        *(u32x4*)(hls + ((j << 8) + (tid ^ (j & 7))) * 16) = tmp[j];
      __syncthreads();
      // gates GEMM: 2 m-tiles x 64 k-steps; W from LDS (w==0) or global
      f32x4 acc0 = {}, acc1 = {};
      if (w == 0) {
#pragma unroll 8
        for (int kt = 0; kt < 2048; kt += 32) {
          int g = (kt >> 3) + lg;
          f16x8 a0 = *(const f16x8*)(hls + ((lr << 8) + (g ^ (lr & 7))) * 16);
          f16x8 a1 = *(const f16x8*)(hls + ((arow1 << 8) + (g ^ (arow1 & 7))) * 16);
          f16x8 wv = *(const f16x8*)(wls + ((lr << 8) + (g ^ (lr & 7))) * 16);
          acc0 = __builtin_amdgcn_mfma_f32_16x16x32_f16(a0, wv, acc0, 0, 0, 0);
          acc1 = __builtin_amdgcn_mfma_f32_16x16x32_f16(a1, wv, acc1, 0, 0, 0);
        }
      } else {
#pragma unroll 8
        for (int kt = 0; kt < 2048; kt += 32) {
          int g = (kt >> 3) + lg;
          f16x8 a0 = *(const f16x8*)(hls + ((lr << 8) + (g ^ (lr & 7))) * 16);
          f16x8 a1 = *(const f16x8*)(hls + ((arow1 << 8) + (g ^ (arow1 & 7))) * 16);
          f16x8 wv = *(const f16x8*)(wp + kt + lg * 8);
          acc0 = __builtin_amdgcn_mfma_f32_16x16x32_f16(a0, wv, acc0, 0, 0, 0);
          acc1 = __builtin_amdgcn_mfma_f32_16x16x32_f16(a1, wv, acc1, 0, 0, 0);
        }
      }
#pragma unroll
      for (int q = 0; q < 4; ++q) {
        int t = lg * 4 + q;              // rows 0..15
        Y[t * 64 + w * 16 + lr] = acc0[q];
        if (lg == 0) Y[(16 + q) * 64 + w * 16 + lr] = acc1[q];  // rows 16..19
      }
    }
    __syncthreads();
    // pointwise: 320 outputs = [20 t][16 j]; thread handles idx=tid (+tid+256)
#pragma unroll
    for (int b2 = 0; b2 < 2; ++b2) {
      int idx = tid + b2 * 256;
      if (idx < 320) {
        int t = idx >> 4, j = idx & 15;
        const float* xp = xg + (size_t)(s * 20 + t) * 8192 + cb + j;
        float g0 = xp[0], g1 = xp[2048], g2 = xp[4096], g3 = xp[6144];
        if (s > 0) {
          g0 += Y[t * 64 + j];
          g1 += Y[t * 64 + 16 + j];
          g2 += Y[t * 64 + 32 + j];
          g3 += Y[t * 64 + 48 + j];
        }
        float cp = (b2 == 0) ? c0 : c1;
        float cn = sigm(g1) * cp + sigm(g0) * tanh_(g2);
        float hv = sigm(g3) * tanh_(cn);
        if (b2 == 0) c0 = cn; else c1 = cn;
        union { _Float16 f; unsigned short u; } cv;
        cv.f = (_Float16)hv;
        int mine = cv.u;
        int oth = __shfl_xor(mine, 1, 64);
        if ((lane & 1) == 0) {
          unsigned int packed = ((unsigned)mine & 0xffffu) | ((unsigned)oth << 16);
          __hip_atomic_store((unsigned int*)(hbuf + (s & 1) * 65536 + t * 2048 + cb + j),
                             packed, __ATOMIC_RELAXED, __HIP_MEMORY_SCOPE_AGENT);
        }
        vf[(size_t)(s * 20 + t) * 2048 + cb + j] = hv;
      }
    }
    if (s == 31) break;
    // grid barrier: h stores drained, then store-only flag handshake
    asm volatile("s_waitcnt vmcnt(0)" ::: "memory");
    __syncthreads();
    if (bid == 0) {
      if (tid > 0 && tid < 128) {
        while (__hip_atomic_load(&flags[tid * 16], __ATOMIC_RELAXED,
                                 __HIP_MEMORY_SCOPE_AGENT) < s + 1)
          __builtin_amdgcn_s_sleep(2);
      }
      __syncthreads();
      if (tid < 8)
        __hip_atomic_store(&go[tid * 16], s + 1, __ATOMIC_RELAXED,
                           __HIP_MEMORY_SCOPE_AGENT);
    } else {
      if (tid == 0) {
        __hip_atomic_store(&flags[bid * 16], s + 1, __ATOMIC_RELAXED,
                           __HIP_MEMORY_SCOPE_AGENT);
        while (__hip_atomic_load(&go[(bid & 7) * 16], __ATOMIC_RELAXED,
                                 __HIP_MEMORY_SCOPE_AGENT) < s + 1)
          __builtin_amdgcn_s_sleep(4);
      }
      __syncthreads();
    }
  }
}

// ---------- group_cls ----------
__global__ __launch_bounds__(256) void gcls(const float* __restrict__ vf,
                                            const float* __restrict__ Wc,
                                            const float* __restrict__ bc,
                                            float* __restrict__ out) {
  const int n = blockIdx.x;
  const int j = threadIdx.x >> 5, l = threadIdx.x & 31;
  const float* v = vf + (size_t)(n * 20 + 19) * 2048;
  const float* w = Wc + (size_t)j * 2048;
  float s = 0.f;
  for (int c = l; c < 2048; c += 32) s += v[c] * w[c];
  for (int off = 16; off > 0; off >>= 1) s += __shfl_down(s, off, 32);
  if (l == 0) out[n * 8 + j] = s + bc[j];
}

// ---------- host ----------
extern "C" void kernel_launch(void* const* d_in, const int* in_sizes, int n_in,
                              void* d_out, int out_size, void* d_ws, size_t ws_size,
                              hipStream_t stream) {
  const float* base_out = (const float*)d_in[0];
  const float* dist = (const float*)d_in[1];
  const float* W1 = (const float*)d_in[2];
  const float* W2 = (const float*)d_in[3];
  const float* w_ih = (const float*)d_in[4];
  const float* w_hh = (const float*)d_in[5];
  const float* b_ih = (const float*)d_in[6];
  const float* b_hh = (const float*)d_in[7];
  const float* Wc = (const float*)d_in[8];
  const float* bc = (const float*)d_in[9];
  float* out = (float*)d_out;

  char* ws = (char*)d_ws;
  const size_t MB = 1048576;
  _Float16* Ahf   = (_Float16*)(ws + 0);            // 60MB  dead after GEMM1
  _Float16* W1hf  = (_Float16*)(ws + 60 * MB);      // 32MB  dead after GEMM1
  _Float16* node1 = (_Float16*)(ws + 92 * MB);      // 60MB
  _Float16* whhhf = (_Float16*)(ws + 152 * MB);     // 32MB
  _Float16* wihhf = (_Float16*)(ws + 184 * MB);     // 48MB
  float* xg       = (float*)(ws + 232 * MB);        // 20MB
  int* go         = (int*)(ws + 252 * MB);          // 8 x 64B
  int* flags      = (int*)(ws + 252 * MB + 1024);   // 128 x 64B
  _Float16* hbuf  = (_Float16*)(ws + 252 * MB + 65536); // 256KB (2 h buffers)
  _Float16* W2hf  = (_Float16*)(ws + 255 * MB);     // 8MB
  _Float16* pooled= (_Float16*)(ws + 263 * MB);     // 3.75MB
  _Float16* n1t   = (_Float16*)(ws + 0);            // 30MB (reuse Ahf)
  _Float16* node2 = (_Float16*)(ws + 30 * MB);      // 30MB

  hipFuncSetAttribute((const void*)gemm256,
                      hipFuncAttributeMaxDynamicSharedMemorySize, 131072);
  hipFuncSetAttribute((const void*)lstm_persist5,
                      hipFuncAttributeMaxDynamicSharedMemorySize, 152576);

  // 1) conversions
  cvt4h<<<30720, 256, 0, stream>>>(base_out, Ahf, 7864320);
  cvt4h<<<16384, 256, 0, stream>>>(W1, W1hf, 4194304);
  cvt4h<<<4096, 256, 0, stream>>>(W2, W2hf, 1048576);
  cvt4h<<<24576, 256, 0, stream>>>(w_ih, wihhf, 6291456);
  cvt4h<<<16384, 256, 0, stream>>>(w_hh, whhhf, 4194304);

  // 2) GEMM1: node1 = base_out·W1^T  [7680,4096]x[4096,4096]
  gemm256<<<dim3(16, 30), 512, 131072, stream>>>(Ahf, W1hf, node1, 7680, 4096, 4096);
  // 3) mix1
  mix1<<<dim3(640, 8), 256, 0, stream>>>(node1, dist, n1t);
  // 4) GEMM2: node2 = n1t·W2^T  [7680,2048]x[2048,2048]
  gemm256<<<dim3(8, 30), 512, 131072, stream>>>(n1t, W2hf, node2, 7680, 2048, 2048);
  // 5) mix2 + pooling
  mix2<<<dim3(640, 4), 256, 0, stream>>>(node2, dist, pooled);
  // 6) xg = pooled·w_ih^T + b_ih + b_hh  [640,3072]x[8192,3072]
  gemm_bt<1><<<dim3(64, 5), 256, 0, stream>>>(pooled, wihhf, xg, b_ih, b_hh,
                                              640, 8192, 3072);
  // 7) persistent LSTM v5 (128 blocks); re-zero barrier state each call
  hipMemsetAsync(go, 0, 65536, stream);
  lstm_persist5<<<128, 256, 152576, stream>>>(whhhf, xg, hbuf, out + 256, go, flags);
  // 8) group_cls
  gcls<<<32, 256, 0, stream>>>(out + 256, Wc, bc, out);
}

// Round 19
// 790.237 us; speedup vs baseline: 1.0917x; 1.0917x over previous
//
#include <hip/hip_runtime.h>

// ---------- types / helpers ----------
typedef _Float16 f16x8 __attribute__((ext_vector_type(8)));
typedef _Float16 f16x4 __attribute__((ext_vector_type(4)));
typedef __attribute__((ext_vector_type(4))) float f32x4;
typedef __attribute__((ext_vector_type(4))) unsigned int u32x4;

#define DI __device__ __forceinline__

DI void gload16(const void* g, void* l) {
  __builtin_amdgcn_global_load_lds(
      (const __attribute__((address_space(1))) unsigned int*)g,
      (__attribute__((address_space(3))) unsigned int*)l, 16, 0, 0);
}

DI float sigm(float x) { return 1.f / (1.f + __expf(-x)); }
DI float tanh_(float x) { return 2.f / (1.f + __expf(-2.f * x)) - 1.f; }

// ---------- f32 -> f16 conversion (x4) ----------
__global__ __launch_bounds__(256) void cvt4h(const float* __restrict__ in,
                                             _Float16* __restrict__ out, int n4) {
  int i = blockIdx.x * 256 + threadIdx.x;
  if (i >= n4) return;
  float4 v = ((const float4*)in)[i];
  f16x4 o;
  o[0] = (_Float16)v.x; o[1] = (_Float16)v.y; o[2] = (_Float16)v.z; o[3] = (_Float16)v.w;
  ((f16x4*)out)[i] = o;
}

// ---------- 256x256 f16 GEMM (R13 exact — best measured: 260us, 0 conflicts) ----------
__global__ __launch_bounds__(512, 2)
void gemm256(const _Float16* __restrict__ A, const _Float16* __restrict__ B,
             _Float16* __restrict__ C, int M, int N, int K) {
  extern __shared__ _Float16 sm[];         // [2][16384] A | [2][16384] B
  _Float16* smA = sm;
  _Float16* smB = sm + 32768;

  const int t512 = threadIdx.x;
  const int lane = t512 & 63, wid = t512 >> 6;
  const int wm = (wid >> 2) * 128, wn = (wid & 3) * 64;
  const int lr = lane & 15, lg = lane >> 4;
  const int sg0 = lg ^ (lr & 7), sg1 = (4 + lg) ^ (lr & 7);  // swizzled k-granules

  const int nwgx = gridDim.x;
  int id = blockIdx.y * nwgx + blockIdx.x;
  int nwg = nwgx * gridDim.y;
  if ((nwg & 7) == 0) id = (id & 7) * (nwg >> 3) + (id >> 3);
  const int n0 = (id % nwgx) * 256;
  const int m0 = (id / nwgx) * 256;

  f32x4 acc[8][4] = {};

#define STAGE(kt, buf)                                                         \
  {                                                                            \
    const int kbase = (kt) * 64;                                               \
    _Pragma("unroll") for (int i = 0; i < 4; ++i) {                            \
      int G = t512 + i * 512;                                                  \
      int r = G >> 3, gs = (G & 7) ^ (r & 7);                                  \
      gload16(A + (size_t)(m0 + r) * K + kbase + gs * 8,                       \
              smA + (buf) * 16384 + G * 8);                                    \
    }                                                                          \
    _Pragma("unroll") for (int i = 0; i < 4; ++i) {                            \
      int G = t512 + i * 512;                                                  \
      int r = G >> 3, gs = (G & 7) ^ (r & 7);                                  \
      gload16(B + (size_t)(n0 + r) * K + kbase + gs * 8,                       \
              smB + (buf) * 16384 + G * 8);                                    \
    }                                                                          \
  }

#define PHASE(m0f, n0f)                                                        \
  {                                                                            \
    f16x8 av[4][2], bv[2][2];                                                  \
    _Pragma("unroll") for (int im = 0; im < 4; ++im) {                         \
      int row = wm + (m0f + im) * 16 + lr;                                     \
      av[im][0] = *(const f16x8*)(Ab + row * 128 + sg0 * 16);                  \
      av[im][1] = *(const f16x8*)(Ab + row * 128 + sg1 * 16);                  \
    }                                                                          \
    _Pragma("unroll") for (int jn = 0; jn < 2; ++jn) {                         \
      int row = wn + (n0f + jn) * 16 + lr;                                     \
      bv[jn][0] = *(const f16x8*)(Bb + row * 128 + sg0 * 16);                  \
      bv[jn][1] = *(const f16x8*)(Bb + row * 128 + sg1 * 16);                  \
    }                                                                          \
    _Pragma("unroll") for (int im = 0; im < 4; ++im)                           \
        _Pragma("unroll") for (int jn = 0; jn < 2; ++jn) {                     \
      acc[m0f + im][n0f + jn] = __builtin_amdgcn_mfma_f32_16x16x32_f16(        \
          av[im][0], bv[jn][0], acc[m0f + im][n0f + jn], 0, 0, 0);             \
      acc[m0f + im][n0f + jn] = __builtin_amdgcn_mfma_f32_16x16x32_f16(        \
          av[im][1], bv[jn][1], acc[m0f + im][n0f + jn], 0, 0, 0);             \
    }                                                                          \
  }

  STAGE(0, 0);
  const int NT = K >> 6;
  for (int t = 0; t < NT; ++t) {
    const int c = t & 1;
    if (t + 1 < NT) {
      STAGE(t + 1, c ^ 1);
      asm volatile("s_waitcnt vmcnt(8)" ::: "memory");  // tile t done; t+1 in flight
    } else {
      asm volatile("s_waitcnt vmcnt(0)" ::: "memory");
    }
    __builtin_amdgcn_s_barrier();
    __builtin_amdgcn_sched_barrier(0);   // fence: no ds_read above barrier
    const char* Ab = (const char*)(smA + c * 16384);
    const char* Bb = (const char*)(smB + c * 16384);
    PHASE(0, 0)
    PHASE(0, 2)
    PHASE(4, 0)
    PHASE(4, 2)
    __builtin_amdgcn_s_barrier();
    __builtin_amdgcn_sched_barrier(0);   // fence: no gload-LDS-write above barrier
  }
#undef STAGE
#undef PHASE

#pragma unroll
  for (int m = 0; m < 8; ++m)
#pragma unroll
    for (int n = 0; n < 4; ++n)
#pragma unroll
      for (int q = 0; q < 4; ++q) {
        int row = m0 + wm + m * 16 + lg * 4 + q;
        int col = n0 + wn + n * 16 + lr;
        C[(size_t)row * N + col] = (_Float16)acc[m][n][q];
      }
}

// ---------- f16 GEMM: C[M,N] = A[M,K] * B[N,K]^T  (m97 structure; xg GEMM) ----------
template <int OUTMODE>
__global__ __launch_bounds__(256, 2)
void gemm_bt(const _Float16* __restrict__ A, const _Float16* __restrict__ B,
             void* __restrict__ Cout, const float* __restrict__ bias1,
             const float* __restrict__ bias2, int M, int N, int K) {
  __shared__ alignas(16) _Float16 Asm[128 * 32];
  __shared__ alignas(16) _Float16 Bsm[128 * 32];
  const int t = threadIdx.x;
  const int lane = t & 63, wid = t >> 6;
  const int m0 = blockIdx.y * 128, n0 = blockIdx.x * 128;
  const int wm = (wid >> 1) * 64, wn = (wid & 1) * 64;
  const int lr = lane & 15, lk = (lane >> 4) * 8, lg = lane >> 4;

  f32x4 acc[4][4] = {};

  const int e0 = t, e1 = t + 256;
  const int ra0 = e0 >> 2, ka0 = (e0 & 3) << 3;
  const int ra1 = e1 >> 2, ka1 = (e1 & 3) << 3;

  for (int kt = 0; kt < K; kt += 32) {
    gload16(A + (size_t)(m0 + ra0) * K + kt + ka0, &Asm[e0 * 8]);
    gload16(A + (size_t)(m0 + ra1) * K + kt + ka1, &Asm[e1 * 8]);
    gload16(B + (size_t)(n0 + ra0) * K + kt + ka0, &Bsm[e0 * 8]);
    gload16(B + (size_t)(n0 + ra1) * K + kt + ka1, &Bsm[e1 * 8]);
    __syncthreads();
    f16x8 af[4], bfr[4];
#pragma unroll
    for (int f = 0; f < 4; ++f) {
      af[f] = *(const f16x8*)&Asm[(wm + f * 16 + lr) * 32 + lk];
      bfr[f] = *(const f16x8*)&Bsm[(wn + f * 16 + lr) * 32 + lk];
    }
#pragma unroll
    for (int i = 0; i < 4; ++i)
#pragma unroll
      for (int j = 0; j < 4; ++j)
        acc[i][j] = __builtin_amdgcn_mfma_f32_16x16x32_f16(af[i], bfr[j], acc[i][j], 0, 0, 0);
    __syncthreads();
  }

#pragma unroll
  for (int i = 0; i < 4; ++i) {
#pragma unroll
    for (int j = 0; j < 4; ++j) {
#pragma unroll
      for (int q = 0; q < 4; ++q) {
        int row = m0 + wm + i * 16 + lg * 4 + q;
        int col = n0 + wn + j * 16 + lr;
        if constexpr (OUTMODE == 0) {
          ((_Float16*)Cout)[(size_t)row * N + col] = (_Float16)acc[i][j][q];
        } else {
          ((float*)Cout)[(size_t)row * N + col] = acc[i][j][q] + bias1[col] + bias2[col];
        }
      }
    }
  }
}

// ---------- mix1 ----------
__global__ __launch_bounds__(256) void mix1(const _Float16* __restrict__ node1,
                                            const float* __restrict__ dist,
                                            _Float16* __restrict__ n1t) {
  __shared__ float ds[288];
  const int nt = blockIdx.x, tid = threadIdx.x;
  for (int i = tid; i < 288; i += 256)
    ds[i] = dist[(size_t)nt * 576 + 288 + i] + dist[(size_t)nt * 576 + i];
  __syncthreads();
  const int c = blockIdx.y * 256 + tid;  // 0..2047
  float s[12];
#pragma unroll
  for (int w = 0; w < 12; ++w) s[w] = 0.f;
#pragma unroll
  for (int k = 0; k < 2; ++k)
#pragma unroll
    for (int v = 0; v < 12; ++v) {
      float x = (float)node1[(size_t)(nt * 12 + v) * 4096 + k * 2048 + c];
      const float* d = &ds[k * 144 + v * 12];
#pragma unroll
      for (int w = 0; w < 12; ++w) s[w] = fmaf(x, d[w], s[w]);
    }
#pragma unroll
  for (int w = 0; w < 12; ++w)
    n1t[(size_t)(nt * 12 + w) * 2048 + c] = (_Float16)fmaxf(s[w], 0.f);
}

// ---------- mix2 + pooling ----------
__global__ __launch_bounds__(256) void mix2(const _Float16* __restrict__ node2,
                                            const float* __restrict__ dist,
                                            _Float16* __restrict__ pooled) {
  __shared__ float db[288], dc[288];
  const int nt = blockIdx.x, tid = threadIdx.x;
  for (int i = tid; i < 288; i += 256) {
    db[i] = dist[(size_t)nt * 576 + 288 + i];
    dc[i] = dist[(size_t)nt * 576 + i];
  }
  __syncthreads();
  const int c = blockIdx.y * 256 + tid;  // 0..1023
  float sb[12], sc[12];
#pragma unroll
  for (int w = 0; w < 12; ++w) { sb[w] = 0.f; sc[w] = 0.f; }
#pragma unroll
  for (int k = 0; k < 2; ++k)
#pragma unroll
    for (int v = 0; v < 12; ++v) {
      float x = (float)node2[(size_t)(nt * 12 + v) * 2048 + k * 1024 + c];
      const float* pb = &db[k * 144 + v * 12];
      const float* pc = &dc[k * 144 + v * 12];
#pragma unroll
      for (int w = 0; w < 12; ++w) { sb[w] = fmaf(x, pb[w], sb[w]); sc[w] = fmaf(x, pc[w], sc[w]); }
    }
  float left = 0.f, right = 0.f, allf = 0.f;
#pragma unroll
  for (int w = 0; w < 6; ++w) left += fmaxf(sb[w], 0.f);
#pragma unroll
  for (int w = 6; w < 12; ++w) right += fmaxf(sb[w], 0.f);
#pragma unroll
  for (int w = 0; w < 12; ++w) allf += fmaxf(sc[w], 0.f);
  pooled[(size_t)nt * 3072 + c] = (_Float16)(left * (1.f / 6.f));
  pooled[(size_t)nt * 3072 + 1024 + c] = (_Float16)(right * (1.f / 6.f));
  pooled[(size_t)nt * 3072 + 2048 + c] = (_Float16)(allf * (1.f / 12.f));
}

// ---------- persistent LSTM v3: W split LDS/L2 (proven R12/R13, 258us) ----------
__global__ __launch_bounds__(256, 1) void lstm_persist3(
    const _Float16* __restrict__ whh,   // [8192,2048] f16
    const float* __restrict__ xg,       // [640,8192]
    _Float16* __restrict__ hbuf,        // 2 buffers, stride 65536 elems
    float* __restrict__ vf,             // [32*20,2048] f32
    int* __restrict__ go,               // 8 lines x 64B (memset 0)
    int* __restrict__ flags) {          // 256 lines x 64B (memset 0)
  extern __shared__ char lds[];
  char* hls = lds;                      // [20][256 granules x16B] swizzled
  char* wls = lds + 81920;              // [16][256 granules x16B] swizzled
  float* Y = (float*)(lds + 147456);    // [20][32]
  const int tid = threadIdx.x, bid = blockIdx.x, cb = bid * 8;
  const int lane = tid & 63, wid = tid >> 6;
  const int mi = wid >> 1, ni = wid & 1;
  const int lr = lane & 15, lg = lane >> 4;
  const int n = ni * 16 + lr;                      // gate g=n>>3, col j=n&7
  const _Float16* wp = whh + (size_t)((n >> 3) * 2048 + cb + (n & 7)) * 2048;
  const int arow = mi * 16 + lr;
  const int arow_c = (arow < 20) ? arow : (16 + (lr & 3));
  const int axor = arow_c & 7;
  const int pt = tid >> 3, pj = tid & 7;           // pointwise (t, col), tid<160
  float c_reg = 0.f;

  // prologue: stage W rows 0..15 (gates i,f for cols cb..cb+7) into LDS
  for (int i = tid; i < 4096; i += 256) {          // 16 rows x 256 granules
    int r = i >> 8, gg = i & 255;
    u32x4 v = *(const u32x4*)(whh + (size_t)((r >> 3) * 2048 + cb + (r & 7)) * 2048 + gg * 8);
    *(u32x4*)(wls + (((r) << 8) + (gg ^ (r & 7))) * 16) = v;
  }

  for (int s = 0; s < 32; ++s) {
    if (s > 0) {
      // stage h(s-1) -> LDS (swizzled), uncached coalesced 16B loads
      const _Float16* hsrc = hbuf + ((s - 1) & 1) * 65536;
      u32x4 tmp[20];
#pragma unroll
      for (int j = 0; j < 20; ++j) {
        asm volatile("global_load_dwordx4 %0, %1, off sc0 sc1"
                     : "=v"(tmp[j]) : "v"(hsrc + j * 2048 + tid * 8));
      }
      asm volatile("s_waitcnt vmcnt(0)" ::: "memory");
      __builtin_amdgcn_sched_barrier(0);
#pragma unroll
      for (int j = 0; j < 20; ++j)
        *(u32x4*)(hls + (((j) << 8) + (tid ^ (j & 7))) * 16) = tmp[j];
      __syncthreads();
      // gates GEMM: h from LDS; W from LDS (ni=0) or cached global (ni=1)
      f32x4 acc = {};
      if (ni == 0) {
#pragma unroll 8
        for (int kt = 0; kt < 2048; kt += 32) {
          int g = (kt >> 3) + lg;
          f16x8 a = *(const f16x8*)(hls + ((arow_c << 8) + (g ^ axor)) * 16);
          f16x8 w = *(const f16x8*)(wls + ((n << 8) + (g ^ (n & 7))) * 16);
          acc = __builtin_amdgcn_mfma_f32_16x16x32_f16(a, w, acc, 0, 0, 0);
        }
      } else {
#pragma unroll 8
        for (int kt = 0; kt < 2048; kt += 32) {
          int g = (kt >> 3) + lg;
          f16x8 a = *(const f16x8*)(hls + ((arow_c << 8) + (g ^ axor)) * 16);
          f16x8 w = *(const f16x8*)(wp + kt + lg * 8);
          acc = __builtin_amdgcn_mfma_f32_16x16x32_f16(a, w, acc, 0, 0, 0);
        }
      }
#pragma unroll
      for (int q = 0; q < 4; ++q) {
        int t = mi * 16 + lg * 4 + q;
        if (t < 20) Y[t * 32 + n] = acc[q];
      }
    }
    __syncthreads();
    if (tid < 160) {
      float g0 = xg[(size_t)(s * 20 + pt) * 8192 + cb + pj];
      float g1 = xg[(size_t)(s * 20 + pt) * 8192 + 2048 + cb + pj];
      float g2 = xg[(size_t)(s * 20 + pt) * 8192 + 4096 + cb + pj];
      float g3 = xg[(size_t)(s * 20 + pt) * 8192 + 6144 + cb + pj];
      if (s > 0) {
        g0 += Y[pt * 32 + pj];
        g1 += Y[pt * 32 + 8 + pj];
        g2 += Y[pt * 32 + 16 + pj];
        g3 += Y[pt * 32 + 24 + pj];
      }
      float cn = sigm(g1) * c_reg + sigm(g0) * tanh_(g2);
      float hv = sigm(g3) * tanh_(cn);
      c_reg = cn;
      union { _Float16 f; unsigned short u; } cv;
      cv.f = (_Float16)hv;
      int mine = cv.u;
      int oth = __shfl_xor(mine, 1, 64);
      if ((tid & 1) == 0) {
        unsigned int packed = ((unsigned)mine & 0xffffu) | ((unsigned)oth << 16);
        __hip_atomic_store((unsigned int*)(hbuf + (s & 1) * 65536 + pt * 2048 + cb + pj),
                           packed, __ATOMIC_RELAXED, __HIP_MEMORY_SCOPE_AGENT);
      }
      vf[(size_t)(s * 20 + pt) * 2048 + cb + pj] = hv;
    }
    if (s == 31) break;
    // grid barrier: h stores drained, then store-only flag handshake
    asm volatile("s_waitcnt vmcnt(0)" ::: "memory");
    __syncthreads();
    if (bid == 0) {
      if (tid > 0) {
        while (__hip_atomic_load(&flags[tid * 16], __ATOMIC_RELAXED,
                                 __HIP_MEMORY_SCOPE_AGENT) < s + 1)
          __builtin_amdgcn_s_sleep(2);
      }
      __syncthreads();
      if (tid < 8)
        __hip_atomic_store(&go[tid * 16], s + 1, __ATOMIC_RELAXED,
                           __HIP_MEMORY_SCOPE_AGENT);
    } else {
      if (tid == 0) {
        __hip_atomic_store(&flags[bid * 16], s + 1, __ATOMIC_RELAXED,
                           __HIP_MEMORY_SCOPE_AGENT);
        while (__hip_atomic_load(&go[(bid & 7) * 16], __ATOMIC_RELAXED,
                                 __HIP_MEMORY_SCOPE_AGENT) < s + 1)
          __builtin_amdgcn_s_sleep(4);
      }
      __syncthreads();
    }
  }
}

// ---------- group_cls ----------
__global__ __launch_bounds__(256) void gcls(const float* __restrict__ vf,
                                            const float* __restrict__ Wc,
                                            const float* __restrict__ bc,
                                            float* __restrict__ out) {
  const int n = blockIdx.x;
  const int j = threadIdx.x >> 5, l = threadIdx.x & 31;
  const float* v = vf + (size_t)(n * 20 + 19) * 2048;
  const float* w = Wc + (size_t)j * 2048;
  float s = 0.f;
  for (int c = l; c < 2048; c += 32) s += v[c] * w[c];
  for (int off = 16; off > 0; off >>= 1) s += __shfl_down(s, off, 32);
  if (l == 0) out[n * 8 + j] = s + bc[j];
}

// ---------- host ----------
extern "C" void kernel_launch(void* const* d_in, const int* in_sizes, int n_in,
                              void* d_out, int out_size, void* d_ws, size_t ws_size,
                              hipStream_t stream) {
  const float* base_out = (const float*)d_in[0];
  const float* dist = (const float*)d_in[1];
  const float* W1 = (const float*)d_in[2];
  const float* W2 = (const float*)d_in[3];
  const float* w_ih = (const float*)d_in[4];
  const float* w_hh = (const float*)d_in[5];
  const float* b_ih = (const float*)d_in[6];
  const float* b_hh = (const float*)d_in[7];
  const float* Wc = (const float*)d_in[8];
  const float* bc = (const float*)d_in[9];
  float* out = (float*)d_out;

  char* ws = (char*)d_ws;
  const size_t MB = 1048576;
  _Float16* Ahf   = (_Float16*)(ws + 0);            // 60MB  dead after GEMM1
  _Float16* W1hf  = (_Float16*)(ws + 60 * MB);      // 32MB  dead after GEMM1
  _Float16* node1 = (_Float16*)(ws + 92 * MB);      // 60MB
  _Float16* whhhf = (_Float16*)(ws + 152 * MB);     // 32MB
  _Float16* wihhf = (_Float16*)(ws + 184 * MB);     // 48MB
  float* xg       = (float*)(ws + 232 * MB);        // 20MB
  int* go         = (int*)(ws + 252 * MB);          // 8 x 64B
  int* flags      = (int*)(ws + 252 * MB + 1024);   // 16KB (256 x 64B)
  _Float16* hbuf  = (_Float16*)(ws + 252 * MB + 65536); // 256KB (2 h buffers)
  _Float16* W2hf  = (_Float16*)(ws + 255 * MB);     // 8MB
  _Float16* pooled= (_Float16*)(ws + 263 * MB);     // 3.75MB
  _Float16* n1t   = (_Float16*)(ws + 0);            // 30MB (reuse Ahf)
  _Float16* node2 = (_Float16*)(ws + 30 * MB);      // 30MB

  hipFuncSetAttribute((const void*)gemm256,
                      hipFuncAttributeMaxDynamicSharedMemorySize, 131072);
  hipFuncSetAttribute((const void*)lstm_persist3,
                      hipFuncAttributeMaxDynamicSharedMemorySize, 150016);

  // 1) conversions
  cvt4h<<<30720, 256, 0, stream>>>(base_out, Ahf, 7864320);
  cvt4h<<<16384, 256, 0, stream>>>(W1, W1hf, 4194304);
  cvt4h<<<4096, 256, 0, stream>>>(W2, W2hf, 1048576);
  cvt4h<<<24576, 256, 0, stream>>>(w_ih, wihhf, 6291456);
  cvt4h<<<16384, 256, 0, stream>>>(w_hh, whhhf, 4194304);

  // 2) GEMM1: node1 = base_out·W1^T  [7680,4096]x[4096,4096]
  gemm256<<<dim3(16, 30), 512, 131072, stream>>>(Ahf, W1hf, node1, 7680, 4096, 4096);
  // 3) mix1
  mix1<<<dim3(640, 8), 256, 0, stream>>>(node1, dist, n1t);
  // 4) GEMM2: node2 = n1t·W2^T  [7680,2048]x[2048,2048]
  gemm256<<<dim3(8, 30), 512, 131072, stream>>>(n1t, W2hf, node2, 7680, 2048, 2048);
  // 5) mix2 + pooling
  mix2<<<dim3(640, 4), 256, 0, stream>>>(node2, dist, pooled);
  // 6) xg = pooled·w_ih^T + b_ih + b_hh  [640,3072]x[8192,3072]
  gemm_bt<1><<<dim3(64, 5), 256, 0, stream>>>(pooled, wihhf, xg, b_ih, b_hh,
                                              640, 8192, 3072);
  // 7) persistent LSTM v3 (one launch); re-zero barrier state each call
  hipMemsetAsync(go, 0, 65536, stream);
  lstm_persist3<<<256, 256, 150016, stream>>>(whhhf, xg, hbuf, out + 256, go, flags);
  // 8) group_cls
  gcls<<<32, 256, 0, stream>>>(out + 256, Wc, bc, out);
}

// Round 20
// 783.005 us; speedup vs baseline: 1.1018x; 1.0092x over previous
//
#include <hip/hip_runtime.h>

// ---------- types / helpers ----------
typedef _Float16 f16x8 __attribute__((ext_vector_type(8)));
typedef _Float16 f16x4 __attribute__((ext_vector_type(4)));
typedef __attribute__((ext_vector_type(4))) float f32x4;
typedef __attribute__((ext_vector_type(4))) unsigned int u32x4;

#define DI __device__ __forceinline__

DI void gload16(const void* g, void* l) {
  __builtin_amdgcn_global_load_lds(
      (const __attribute__((address_space(1))) unsigned int*)g,
      (__attribute__((address_space(3))) unsigned int*)l, 16, 0, 0);
}

DI float sigm(float x) { return 1.f / (1.f + __expf(-x)); }
DI float tanh_(float x) { return 2.f / (1.f + __expf(-2.f * x)) - 1.f; }

// ---------- f32 -> f16 conversion (x4) ----------
__global__ __launch_bounds__(256) void cvt4h(const float* __restrict__ in,
                                             _Float16* __restrict__ out, int n4) {
  int i = blockIdx.x * 256 + threadIdx.x;
  if (i >= n4) return;
  float4 v = ((const float4*)in)[i];
  f16x4 o;
  o[0] = (_Float16)v.x; o[1] = (_Float16)v.y; o[2] = (_Float16)v.z; o[3] = (_Float16)v.w;
  ((f16x4*)out)[i] = o;
}

// ---------- 256x256 f16 GEMM — R20: 8-phase derived-waits deep pipeline ----------
// 2 K-tiles/iter (buf0=even tile, buf1=odd, fixed). Per phase: {dedup'd
// ds_reads -> 1 stage-unit issue -> [vmcnt(6) @P4/P8] -> s_barrier ->
// lgkmcnt(0) -> setprio(1) 16 MFMA setprio(0) -> s_barrier}. Stage units are
// interleaved row-sets matching quadrant reads (A-u: rows {0-63,128-191}u=0;
// B-u: (r>>5)&1==u) so each unit's last read precedes overwrite by >=1 phase.
// vmcnt(6) = 3 units in flight; never drains in-loop. 24 ds_read/K-tile/wave
// (vs 48 in the 1-phase R13 loop).
__global__ __launch_bounds__(512, 2)
void gemm256(const _Float16* __restrict__ A, const _Float16* __restrict__ B,
             _Float16* __restrict__ C, int M, int N, int K) {
  extern __shared__ _Float16 sm[];         // [2][16384] A | [2][16384] B
  _Float16* smA = sm;
  _Float16* smB = sm + 32768;

  const int t512 = threadIdx.x;
  const int lane = t512 & 63, wid = t512 >> 6;
  const int wm = (wid >> 2) * 128, wn = (wid & 3) * 64;
  const int lr = lane & 15, lg = lane >> 4;
  const int sg0 = lg ^ (lr & 7), sg1 = (4 + lg) ^ (lr & 7);
  const int so = lane >> 3, sgr = lane & 7;   // staging: row-in-octet, granule

  const int nwgx = gridDim.x;
  int id = blockIdx.y * nwgx + blockIdx.x;
  int nwg = nwgx * gridDim.y;
  if ((nwg & 7) == 0) id = (id & 7) * (nwg >> 3) + (id >> 3);
  const int n0 = (id % nwgx) * 256;
  const int m0 = (id / nwgx) * 256;

  f32x4 acc[8][4] = {};

// stage one A-unit (16 octets = rows {0-63,128-191} for u=0): 2 gload16/thread
#define STG_A(u, kt, b)                                                        \
  { _Pragma("unroll") for (int i_ = 0; i_ < 2; ++i_) {                         \
      int s_ = i_ * 8 + wid;                                                   \
      int o_ = ((s_ >> 3) << 4) + (u) * 8 + (s_ & 7);                          \
      int pr_ = o_ * 8 + so;                                                   \
      gload16(A + (size_t)(m0 + pr_) * K + (kt) * 64 + (sgr ^ (pr_ & 7)) * 8,  \
              smA + (b) * 16384 + o_ * 512 + lane * 8); } }
#define STG_B(u, kt, b)                                                        \
  { _Pragma("unroll") for (int i_ = 0; i_ < 2; ++i_) {                         \
      int s_ = i_ * 8 + wid;                                                   \
      int o_ = ((s_ >> 2) << 3) + (u) * 4 + (s_ & 3);                          \
      int pr_ = o_ * 8 + so;                                                   \
      gload16(B + (size_t)(n0 + pr_) * K + (kt) * 64 + (sgr ^ (pr_ & 7)) * 8,  \
              smB + (b) * 16384 + o_ * 512 + lane * 8); } }

#define RD_A03(Xb) _Pragma("unroll") for (int f_ = 0; f_ < 4; ++f_) {          \
    int row = wm + f_ * 16 + lr;                                               \
    av0[f_][0] = *(const f16x8*)((Xb) + row * 128 + sg0 * 16);                 \
    av0[f_][1] = *(const f16x8*)((Xb) + row * 128 + sg1 * 16); }
#define RD_A47(Xb) _Pragma("unroll") for (int f_ = 0; f_ < 4; ++f_) {          \
    int row = wm + (4 + f_) * 16 + lr;                                         \
    av1[f_][0] = *(const f16x8*)((Xb) + row * 128 + sg0 * 16);                 \
    av1[f_][1] = *(const f16x8*)((Xb) + row * 128 + sg1 * 16); }
#define RD_B01(Xb) _Pragma("unroll") for (int j_ = 0; j_ < 2; ++j_) {          \
    int row = wn + j_ * 16 + lr;                                               \
    bv0[j_][0] = *(const f16x8*)((Xb) + row * 128 + sg0 * 16);                 \
    bv0[j_][1] = *(const f16x8*)((Xb) + row * 128 + sg1 * 16); }
#define RD_B23(Xb) _Pragma("unroll") for (int j_ = 0; j_ < 2; ++j_) {          \
    int row = wn + (2 + j_) * 16 + lr;                                         \
    bv1[j_][0] = *(const f16x8*)((Xb) + row * 128 + sg0 * 16);                 \
    bv1[j_][1] = *(const f16x8*)((Xb) + row * 128 + sg1 * 16); }

#define MQ(AV, BV, FB, NB)                                                     \
  __builtin_amdgcn_s_setprio(1);                                               \
  _Pragma("unroll") for (int f_ = 0; f_ < 4; ++f_)                             \
  _Pragma("unroll") for (int j_ = 0; j_ < 2; ++j_) {                           \
    acc[(FB) + f_][(NB) + j_] = __builtin_amdgcn_mfma_f32_16x16x32_f16(        \
        AV[f_][0], BV[j_][0], acc[(FB) + f_][(NB) + j_], 0, 0, 0);             \
    acc[(FB) + f_][(NB) + j_] = __builtin_amdgcn_mfma_f32_16x16x32_f16(        \
        AV[f_][1], BV[j_][1], acc[(FB) + f_][(NB) + j_], 0, 0, 0); }           \
  __builtin_amdgcn_s_setprio(0);

#define BARIN  __builtin_amdgcn_s_barrier();                                   \
               asm volatile("s_waitcnt lgkmcnt(0)" ::: "memory");              \
               __builtin_amdgcn_sched_barrier(0);
#define BAROUT __builtin_amdgcn_s_barrier();                                   \
               __builtin_amdgcn_sched_barrier(0);

  const char* Ab0 = (const char*)smA;
  const char* Ab1 = (const char*)(smA + 16384);
  const char* Bb0 = (const char*)smB;
  const char* Bb1 = (const char*)(smB + 16384);

  // prologue: tile0 (4 units) + tile1 (3 units); wait tile0 resident
  STG_A(0, 0, 0) STG_B(0, 0, 0) STG_B(1, 0, 0) STG_A(1, 0, 0)
  STG_A(0, 1, 1) STG_B(0, 1, 1) STG_B(1, 1, 1)
  asm volatile("s_waitcnt vmcnt(6)" ::: "memory");
  __builtin_amdgcn_s_barrier();
  __builtin_amdgcn_sched_barrier(0);

  const int NI = K >> 7;   // iterations of 2 K-tiles
  f16x8 av0[4][2], av1[4][2], bv0[2][2], bv1[2][2];
  for (int it = 0; it < NI; ++it) {
    const int tb = 2 * it + 1, sa = 2 * it + 2, sb = 2 * it + 3;
    const bool pre = (it + 1 < NI);
    // P1: reads buf0 A03+B01; stage buf1.A1(tb) just-in-time
    RD_A03(Ab0) RD_B01(Bb0)
    STG_A(1, tb, 1)
    BARIN  MQ(av0, bv0, 0, 0)  BAROUT
    // P2: reads buf0 B23; stage buf0.A0(sa)
    RD_B23(Bb0)
    if (pre) STG_A(0, sa, 0)
    BARIN  MQ(av0, bv1, 0, 2)  BAROUT
    // P3: reads buf0 A47; stage buf0.B0(sa)
    RD_A47(Ab0)
    if (pre) STG_B(0, sa, 0)
    BARIN  MQ(av1, bv1, 4, 2)  BAROUT
    // P4: no reads (bv0, av1 held); stage buf0.B1(sa); counted wait -> buf1 ready
    if (pre) {
      STG_B(1, sa, 0)
      asm volatile("s_waitcnt vmcnt(6)" ::: "memory");
    } else {
      asm volatile("s_waitcnt vmcnt(0)" ::: "memory");
    }
    BARIN  MQ(av1, bv0, 4, 0)  BAROUT
    // P5: reads buf1 A03+B01; stage buf0.A1(sa)
    RD_A03(Ab1) RD_B01(Bb1)
    if (pre) STG_A(1, sa, 0)
    BARIN  MQ(av0, bv0, 0, 0)  BAROUT
    // P6: reads buf1 B23; stage buf1.A0(sb)
    RD_B23(Bb1)
    if (pre) STG_A(0, sb, 1)
    BARIN  MQ(av0, bv1, 0, 2)  BAROUT
    // P7: reads buf1 A47; stage buf1.B0(sb)
    RD_A47(Ab1)
    if (pre) STG_B(0, sb, 1)
    BARIN  MQ(av1, bv1, 4, 2)  BAROUT
    // P8: no reads; stage buf1.B1(sb); counted wait -> buf0(sa) ready for next P1
    if (pre) {
      STG_B(1, sb, 1)
      asm volatile("s_waitcnt vmcnt(6)" ::: "memory");
    }
    BARIN  MQ(av1, bv0, 4, 0)  BAROUT
  }
#undef STG_A
#undef STG_B
#undef RD_A03
#undef RD_A47
#undef RD_B01
#undef RD_B23
#undef MQ
#undef BARIN
#undef BAROUT

#pragma unroll
  for (int m = 0; m < 8; ++m)
#pragma unroll
    for (int n = 0; n < 4; ++n)
#pragma unroll
      for (int q = 0; q < 4; ++q) {
        int row = m0 + wm + m * 16 + lg * 4 + q;
        int col = n0 + wn + n * 16 + lr;
        C[(size_t)row * N + col] = (_Float16)acc[m][n][q];
      }
}

// ---------- f16 GEMM: C[M,N] = A[M,K] * B[N,K]^T  (m97 structure; xg GEMM) ----------
template <int OUTMODE>
__global__ __launch_bounds__(256, 2)
void gemm_bt(const _Float16* __restrict__ A, const _Float16* __restrict__ B,
             void* __restrict__ Cout, const float* __restrict__ bias1,
             const float* __restrict__ bias2, int M, int N, int K) {
  __shared__ alignas(16) _Float16 Asm[128 * 32];
  __shared__ alignas(16) _Float16 Bsm[128 * 32];
  const int t = threadIdx.x;
  const int lane = t & 63, wid = t >> 6;
  const int m0 = blockIdx.y * 128, n0 = blockIdx.x * 128;
  const int wm = (wid >> 1) * 64, wn = (wid & 1) * 64;
  const int lr = lane & 15, lk = (lane >> 4) * 8, lg = lane >> 4;

  f32x4 acc[4][4] = {};

  const int e0 = t, e1 = t + 256;
  const int ra0 = e0 >> 2, ka0 = (e0 & 3) << 3;
  const int ra1 = e1 >> 2, ka1 = (e1 & 3) << 3;

  for (int kt = 0; kt < K; kt += 32) {
    gload16(A + (size_t)(m0 + ra0) * K + kt + ka0, &Asm[e0 * 8]);
    gload16(A + (size_t)(m0 + ra1) * K + kt + ka1, &Asm[e1 * 8]);
    gload16(B + (size_t)(n0 + ra0) * K + kt + ka0, &Bsm[e0 * 8]);
    gload16(B + (size_t)(n0 + ra1) * K + kt + ka1, &Bsm[e1 * 8]);
    __syncthreads();
    f16x8 af[4], bfr[4];
#pragma unroll
    for (int f = 0; f < 4; ++f) {
      af[f] = *(const f16x8*)&Asm[(wm + f * 16 + lr) * 32 + lk];
      bfr[f] = *(const f16x8*)&Bsm[(wn + f * 16 + lr) * 32 + lk];
    }
#pragma unroll
    for (int i = 0; i < 4; ++i)
#pragma unroll
      for (int j = 0; j < 4; ++j)
        acc[i][j] = __builtin_amdgcn_mfma_f32_16x16x32_f16(af[i], bfr[j], acc[i][j], 0, 0, 0);
    __syncthreads();
  }

#pragma unroll
  for (int i = 0; i < 4; ++i) {
#pragma unroll
    for (int j = 0; j < 4; ++j) {
#pragma unroll
      for (int q = 0; q < 4; ++q) {
        int row = m0 + wm + i * 16 + lg * 4 + q;
        int col = n0 + wn + j * 16 + lr;
        if constexpr (OUTMODE == 0) {
          ((_Float16*)Cout)[(size_t)row * N + col] = (_Float16)acc[i][j][q];
        } else {
          ((float*)Cout)[(size_t)row * N + col] = acc[i][j][q] + bias1[col] + bias2[col];
        }
      }
    }
  }
}

// ---------- mix1 ----------
__global__ __launch_bounds__(256) void mix1(const _Float16* __restrict__ node1,
                                            const float* __restrict__ dist,
                                            _Float16* __restrict__ n1t) {
  __shared__ float ds[288];
  const int nt = blockIdx.x, tid = threadIdx.x;
  for (int i = tid; i < 288; i += 256)
    ds[i] = dist[(size_t)nt * 576 + 288 + i] + dist[(size_t)nt * 576 + i];
  __syncthreads();
  const int c = blockIdx.y * 256 + tid;  // 0..2047
  float s[12];
#pragma unroll
  for (int w = 0; w < 12; ++w) s[w] = 0.f;
#pragma unroll
  for (int k = 0; k < 2; ++k)
#pragma unroll
    for (int v = 0; v < 12; ++v) {
      float x = (float)node1[(size_t)(nt * 12 + v) * 4096 + k * 2048 + c];
      const float* d = &ds[k * 144 + v * 12];
#pragma unroll
      for (int w = 0; w < 12; ++w) s[w] = fmaf(x, d[w], s[w]);
    }
#pragma unroll
  for (int w = 0; w < 12; ++w)
    n1t[(size_t)(nt * 12 + w) * 2048 + c] = (_Float16)fmaxf(s[w], 0.f);
}

// ---------- mix2 + pooling ----------
__global__ __launch_bounds__(256) void mix2(const _Float16* __restrict__ node2,
                                            const float* __restrict__ dist,
                                            _Float16* __restrict__ pooled) {
  __shared__ float db[288], dc[288];
  const int nt = blockIdx.x, tid = threadIdx.x;
  for (int i = tid; i < 288; i += 256) {
    db[i] = dist[(size_t)nt * 576 + 288 + i];
    dc[i] = dist[(size_t)nt * 576 + i];
  }
  __syncthreads();
  const int c = blockIdx.y * 256 + tid;  // 0..1023
  float sb[12], sc[12];
#pragma unroll
  for (int w = 0; w < 12; ++w) { sb[w] = 0.f; sc[w] = 0.f; }
#pragma unroll
  for (int k = 0; k < 2; ++k)
#pragma unroll
    for (int v = 0; v < 12; ++v) {
      float x = (float)node2[(size_t)(nt * 12 + v) * 2048 + k * 1024 + c];
      const float* pb = &db[k * 144 + v * 12];
      const float* pc = &dc[k * 144 + v * 12];
#pragma unroll
      for (int w = 0; w < 12; ++w) { sb[w] = fmaf(x, pb[w], sb[w]); sc[w] = fmaf(x, pc[w], sc[w]); }
    }
  float left = 0.f, right = 0.f, allf = 0.f;
#pragma unroll
  for (int w = 0; w < 6; ++w) left += fmaxf(sb[w], 0.f);
#pragma unroll
  for (int w = 6; w < 12; ++w) right += fmaxf(sb[w], 0.f);
#pragma unroll
  for (int w = 0; w < 12; ++w) allf += fmaxf(sc[w], 0.f);
  pooled[(size_t)nt * 3072 + c] = (_Float16)(left * (1.f / 6.f));
  pooled[(size_t)nt * 3072 + 1024 + c] = (_Float16)(right * (1.f / 6.f));
  pooled[(size_t)nt * 3072 + 2048 + c] = (_Float16)(allf * (1.f / 12.f));
}

// ---------- persistent LSTM v3: W split LDS/L2 (proven R12/R13, 258us) ----------
__global__ __launch_bounds__(256, 1) void lstm_persist3(
    const _Float16* __restrict__ whh,   // [8192,2048] f16
    const float* __restrict__ xg,       // [640,8192]
    _Float16* __restrict__ hbuf,        // 2 buffers, stride 65536 elems
    float* __restrict__ vf,             // [32*20,2048] f32
    int* __restrict__ go,               // 8 lines x 64B (memset 0)
    int* __restrict__ flags) {          // 256 lines x 64B (memset 0)
  extern __shared__ char lds[];
  char* hls = lds;                      // [20][256 granules x16B] swizzled
  char* wls = lds + 81920;              // [16][256 granules x16B] swizzled
  float* Y = (float*)(lds + 147456);    // [20][32]
  const int tid = threadIdx.x, bid = blockIdx.x, cb = bid * 8;
  const int lane = tid & 63, wid = tid >> 6;
  const int mi = wid >> 1, ni = wid & 1;
  const int lr = lane & 15, lg = lane >> 4;
  const int n = ni * 16 + lr;                      // gate g=n>>3, col j=n&7
  const _Float16* wp = whh + (size_t)((n >> 3) * 2048 + cb + (n & 7)) * 2048;
  const int arow = mi * 16 + lr;
  const int arow_c = (arow < 20) ? arow : (16 + (lr & 3));
  const int axor = arow_c & 7;
  const int pt = tid >> 3, pj = tid & 7;           // pointwise (t, col), tid<160
  float c_reg = 0.f;

  // prologue: stage W rows 0..15 (gates i,f for cols cb..cb+7) into LDS
  for (int i = tid; i < 4096; i += 256) {          // 16 rows x 256 granules
    int r = i >> 8, gg = i & 255;
    u32x4 v = *(const u32x4*)(whh + (size_t)((r >> 3) * 2048 + cb + (r & 7)) * 2048 + gg * 8);
    *(u32x4*)(wls + (((r) << 8) + (gg ^ (r & 7))) * 16) = v;
  }

  for (int s = 0; s < 32; ++s) {
    if (s > 0) {
      // stage h(s-1) -> LDS (swizzled), uncached coalesced 16B loads
      const _Float16* hsrc = hbuf + ((s - 1) & 1) * 65536;
      u32x4 tmp[20];
#pragma unroll
      for (int j = 0; j < 20; ++j) {
        asm volatile("global_load_dwordx4 %0, %1, off sc0 sc1"
                     : "=v"(tmp[j]) : "v"(hsrc + j * 2048 + tid * 8));
      }
      asm volatile("s_waitcnt vmcnt(0)" ::: "memory");
      __builtin_amdgcn_sched_barrier(0);
#pragma unroll
      for (int j = 0; j < 20; ++j)
        *(u32x4*)(hls + (((j) << 8) + (tid ^ (j & 7))) * 16) = tmp[j];
      __syncthreads();
      // gates GEMM: h from LDS; W from LDS (ni=0) or cached global (ni=1)
      f32x4 acc = {};
      if (ni == 0) {
#pragma unroll 8
        for (int kt = 0; kt < 2048; kt += 32) {
          int g = (kt >> 3) + lg;
          f16x8 a = *(const f16x8*)(hls + ((arow_c << 8) + (g ^ axor)) * 16);
          f16x8 w = *(const f16x8*)(wls + ((n << 8) + (g ^ (n & 7))) * 16);
          acc = __builtin_amdgcn_mfma_f32_16x16x32_f16(a, w, acc, 0, 0, 0);
        }
      } else {
#pragma unroll 8
        for (int kt = 0; kt < 2048; kt += 32) {
          int g = (kt >> 3) + lg;
          f16x8 a = *(const f16x8*)(hls + ((arow_c << 8) + (g ^ axor)) * 16);
          f16x8 w = *(const f16x8*)(wp + kt + lg * 8);
          acc = __builtin_amdgcn_mfma_f32_16x16x32_f16(a, w, acc, 0, 0, 0);
        }
      }
#pragma unroll
      for (int q = 0; q < 4; ++q) {
        int t = mi * 16 + lg * 4 + q;
        if (t < 20) Y[t * 32 + n] = acc[q];
      }
    }
    __syncthreads();
    if (tid < 160) {
      float g0 = xg[(size_t)(s * 20 + pt) * 8192 + cb + pj];
      float g1 = xg[(size_t)(s * 20 + pt) * 8192 + 2048 + cb + pj];
      float g2 = xg[(size_t)(s * 20 + pt) * 8192 + 4096 + cb + pj];
      float g3 = xg[(size_t)(s * 20 + pt) * 8192 + 6144 + cb + pj];
      if (s > 0) {
        g0 += Y[pt * 32 + pj];
        g1 += Y[pt * 32 + 8 + pj];
        g2 += Y[pt * 32 + 16 + pj];
        g3 += Y[pt * 32 + 24 + pj];
      }
      float cn = sigm(g1) * c_reg + sigm(g0) * tanh_(g2);
      float hv = sigm(g3) * tanh_(cn);
      c_reg = cn;
      union { _Float16 f; unsigned short u; } cv;
      cv.f = (_Float16)hv;
      int mine = cv.u;
      int oth = __shfl_xor(mine, 1, 64);
      if ((tid & 1) == 0) {
        unsigned int packed = ((unsigned)mine & 0xffffu) | ((unsigned)oth << 16);
        __hip_atomic_store((unsigned int*)(hbuf + (s & 1) * 65536 + pt * 2048 + cb + pj),
                           packed, __ATOMIC_RELAXED, __HIP_MEMORY_SCOPE_AGENT);
      }
      vf[(size_t)(s * 20 + pt) * 2048 + cb + pj] = hv;
    }
    if (s == 31) break;
    // grid barrier: h stores drained, then store-only flag handshake
    asm volatile("s_waitcnt vmcnt(0)" ::: "memory");
    __syncthreads();
    if (bid == 0) {
      if (tid > 0) {
        while (__hip_atomic_load(&flags[tid * 16], __ATOMIC_RELAXED,
                                 __HIP_MEMORY_SCOPE_AGENT) < s + 1)
          __builtin_amdgcn_s_sleep(2);
      }
      __syncthreads();
      if (tid < 8)
        __hip_atomic_store(&go[tid * 16], s + 1, __ATOMIC_RELAXED,
                           __HIP_MEMORY_SCOPE_AGENT);
    } else {
      if (tid == 0) {
        __hip_atomic_store(&flags[bid * 16], s + 1, __ATOMIC_RELAXED,
                           __HIP_MEMORY_SCOPE_AGENT);
        while (__hip_atomic_load(&go[(bid & 7) * 16], __ATOMIC_RELAXED,
                                 __HIP_MEMORY_SCOPE_AGENT) < s + 1)
          __builtin_amdgcn_s_sleep(4);
      }
      __syncthreads();
    }
  }
}

// ---------- group_cls ----------
__global__ __launch_bounds__(256) void gcls(const float* __restrict__ vf,
                                            const float* __restrict__ Wc,
                                            const float* __restrict__ bc,
                                            float* __restrict__ out) {
  const int n = blockIdx.x;
  const int j = threadIdx.x >> 5, l = threadIdx.x & 31;
  const float* v = vf + (size_t)(n * 20 + 19) * 2048;
  const float* w = Wc + (size_t)j * 2048;
  float s = 0.f;
  for (int c = l; c < 2048; c += 32) s += v[c] * w[c];
  for (int off = 16; off > 0; off >>= 1) s += __shfl_down(s, off, 32);
  if (l == 0) out[n * 8 + j] = s + bc[j];
}

// ---------- host ----------
extern "C" void kernel_launch(void* const* d_in, const int* in_sizes, int n_in,
                              void* d_out, int out_size, void* d_ws, size_t ws_size,
                              hipStream_t stream) {
  const float* base_out = (const float*)d_in[0];
  const float* dist = (const float*)d_in[1];
  const float* W1 = (const float*)d_in[2];
  const float* W2 = (const float*)d_in[3];
  const float* w_ih = (const float*)d_in[4];
  const float* w_hh = (const float*)d_in[5];
  const float* b_ih = (const float*)d_in[6];
  const float* b_hh = (const float*)d_in[7];
  const float* Wc = (const float*)d_in[8];
  const float* bc = (const float*)d_in[9];
  float* out = (float*)d_out;

  char* ws = (char*)d_ws;
  const size_t MB = 1048576;
  _Float16* Ahf   = (_Float16*)(ws + 0);            // 60MB  dead after GEMM1
  _Float16* W1hf  = (_Float16*)(ws + 60 * MB);      // 32MB  dead after GEMM1
  _Float16* node1 = (_Float16*)(ws + 92 * MB);      // 60MB
  _Float16* whhhf = (_Float16*)(ws + 152 * MB);     // 32MB
  _Float16* wihhf = (_Float16*)(ws + 184 * MB);     // 48MB
  float* xg       = (float*)(ws + 232 * MB);        // 20MB
  int* go         = (int*)(ws + 252 * MB);          // 8 x 64B
  int* flags      = (int*)(ws + 252 * MB + 1024);   // 16KB (256 x 64B)
  _Float16* hbuf  = (_Float16*)(ws + 252 * MB + 65536); // 256KB (2 h buffers)
  _Float16* W2hf  = (_Float16*)(ws + 255 * MB);     // 8MB
  _Float16* pooled= (_Float16*)(ws + 263 * MB);     // 3.75MB
  _Float16* n1t   = (_Float16*)(ws + 0);            // 30MB (reuse Ahf)
  _Float16* node2 = (_Float16*)(ws + 30 * MB);      // 30MB

  hipFuncSetAttribute((const void*)gemm256,
                      hipFuncAttributeMaxDynamicSharedMemorySize, 131072);
  hipFuncSetAttribute((const void*)lstm_persist3,
                      hipFuncAttributeMaxDynamicSharedMemorySize, 150016);

  // 1) conversions
  cvt4h<<<30720, 256, 0, stream>>>(base_out, Ahf, 7864320);
  cvt4h<<<16384, 256, 0, stream>>>(W1, W1hf, 4194304);
  cvt4h<<<4096, 256, 0, stream>>>(W2, W2hf, 1048576);
  cvt4h<<<24576, 256, 0, stream>>>(w_ih, wihhf, 6291456);
  cvt4h<<<16384, 256, 0, stream>>>(w_hh, whhhf, 4194304);

  // 2) GEMM1: node1 = base_out·W1^T  [7680,4096]x[4096,4096]
  gemm256<<<dim3(16, 30), 512, 131072, stream>>>(Ahf, W1hf, node1, 7680, 4096, 4096);
  // 3) mix1
  mix1<<<dim3(640, 8), 256, 0, stream>>>(node1, dist, n1t);
  // 4) GEMM2: node2 = n1t·W2^T  [7680,2048]x[2048,2048]
  gemm256<<<dim3(8, 30), 512, 131072, stream>>>(n1t, W2hf, node2, 7680, 2048, 2048);
  // 5) mix2 + pooling
  mix2<<<dim3(640, 4), 256, 0, stream>>>(node2, dist, pooled);
  // 6) xg = pooled·w_ih^T + b_ih + b_hh  [640,3072]x[8192,3072]
  gemm_bt<1><<<dim3(64, 5), 256, 0, stream>>>(pooled, wihhf, xg, b_ih, b_hh,
                                              640, 8192, 3072);
  // 7) persistent LSTM v3 (one launch); re-zero barrier state each call
  hipMemsetAsync(go, 0, 65536, stream);
  lstm_persist3<<<256, 256, 150016, stream>>>(whhhf, xg, hbuf, out + 256, go, flags);
  // 8) group_cls
  gcls<<<32, 256, 0, stream>>>(out + 256, Wc, bc, out);
}